// Round 1
// baseline (298.562 us; speedup 1.0000x reference)
//
#include <hip/hip_runtime.h>
#include <hip/hip_bf16.h>
#include <math.h>

// Problem constants (fixed by setup_inputs)
#define BB   256     // batch
#define DIN  2048
#define DD   512
#define CC   1000
#define NN   50000
#define MM   (NN + BB)   // 50256
#define FILTER_K 100

// ---------------- workspace layout (float elements) ----------------
#define Z_OFF     0                        // z: [256][512]           131072
#define P_OFF     (Z_OFF + BB*DD)          // p: [256][1000]          256000
#define ENTN_OFF  (P_OFF + BB*CC)          // ent_new: [256]
#define CLS_OFF   (ENTN_OFF + BB)          // cls (int): [256]
#define CNT_OFF   (CLS_OFF + BB)           // counts (int): [1024]
#define OFFS_OFF  (CNT_OFF + 1024)         // offsets (int): [1024]
#define CUR_OFF   (OFFS_OFF + 1024)        // cursor (int): [1024]
#define ENTS_OFF  (CUR_OFF + 1024)         // ent_s: [M]
#define IDXS_OFF  (ENTS_OFF + MM)          // idx_s (int): [M]
#define WN_OFF    (IDXS_OFF + MM)          // wn: [1000][512]         512000
// total ~1.0M floats ~4 MB

// ================= K1: z = x @ Wf  (split-K, atomic accumulate) ==========
#define BM1 64
#define BN1 64
#define BK1 16
__global__ __launch_bounds__(256) void gemm_split_k(
    const float* __restrict__ A,  // [M][K]
    const float* __restrict__ B,  // [K][N]
    float* __restrict__ C,        // [M][N], pre-zeroed
    int M, int N, int K, int klen) {
  __shared__ float As[BK1][BM1 + 4];
  __shared__ float Bs[BK1][BN1 + 4];
  const int m0 = blockIdx.y * BM1;
  const int n0 = blockIdx.x * BN1;
  const int k0 = blockIdx.z * klen;
  const int tid = threadIdx.x;
  const int ar = tid >> 2, ac4 = (tid & 3) * 4;    // A tile: 64 rows x 16 k
  const int br = tid >> 4, bc4 = (tid & 15) * 4;   // B tile: 16 k x 64 n
  const int tm = (tid >> 4) * 4, tn = (tid & 15) * 4;
  float acc[4][4] = {};
  for (int kk = 0; kk < klen; kk += BK1) {
    float4 av = *(const float4*)&A[(size_t)(m0 + ar) * K + (k0 + kk + ac4)];
    float4 bv = *(const float4*)&B[(size_t)(k0 + kk + br) * N + (n0 + bc4)];
    __syncthreads();
    As[ac4 + 0][ar] = av.x; As[ac4 + 1][ar] = av.y;
    As[ac4 + 2][ar] = av.z; As[ac4 + 3][ar] = av.w;
    *(float4*)&Bs[br][bc4] = bv;
    __syncthreads();
#pragma unroll
    for (int q = 0; q < BK1; ++q) {
      float4 a = *(const float4*)&As[q][tm];
      float4 b = *(const float4*)&Bs[q][tn];
      float aa[4] = {a.x, a.y, a.z, a.w};
      float bb[4] = {b.x, b.y, b.z, b.w};
#pragma unroll
      for (int i = 0; i < 4; ++i)
#pragma unroll
        for (int j = 0; j < 4; ++j) acc[i][j] += aa[i] * bb[j];
    }
  }
#pragma unroll
  for (int i = 0; i < 4; ++i)
#pragma unroll
    for (int j = 0; j < 4; ++j)
      atomicAdd(&C[(size_t)(m0 + tm + i) * N + (n0 + tn + j)], acc[i][j]);
}

// ============ K2/K5: C = A @ B^T (+bias)  A:[M][K]  B:[Nn][K] ============
#define BM2 32
#define BN2 32
#define BK2 32
__global__ __launch_bounds__(256) void gemm_abt(
    const float* __restrict__ A, const float* __restrict__ B,
    const float* __restrict__ bias, float* __restrict__ C,
    int M, int N, int K) {
  __shared__ float As[BM2][BK2 + 4];
  __shared__ float Bs[BN2][BK2 + 4];
  const int m0 = blockIdx.y * BM2;
  const int n0 = blockIdx.x * BN2;
  const int tid = threadIdx.x;
  const int r = tid >> 3, c4 = (tid & 7) * 4;   // 32 rows x 8 float4
  const int tm = (tid >> 4) * 2, tn = (tid & 15) * 2;
  float acc[2][2] = {};
  for (int k0 = 0; k0 < K; k0 += BK2) {
    float4 av = *(const float4*)&A[(size_t)(m0 + r) * K + k0 + c4];
    float4 bv = make_float4(0.f, 0.f, 0.f, 0.f);
    if (n0 + r < N) bv = *(const float4*)&B[(size_t)(n0 + r) * K + k0 + c4];
    __syncthreads();
    *(float4*)&As[r][c4] = av;
    *(float4*)&Bs[r][c4] = bv;
    __syncthreads();
#pragma unroll
    for (int q = 0; q < BK2; ++q) {
      float a0 = As[tm][q], a1 = As[tm + 1][q];
      float b0 = Bs[tn][q], b1 = Bs[tn + 1][q];
      acc[0][0] += a0 * b0; acc[0][1] += a0 * b1;
      acc[1][0] += a1 * b0; acc[1][1] += a1 * b1;
    }
  }
#pragma unroll
  for (int i = 0; i < 2; ++i)
#pragma unroll
    for (int j = 0; j < 2; ++j) {
      int n = n0 + tn + j;
      if (n < N) {
        float v = acc[i][j];
        if (bias) v += bias[n];
        C[(size_t)(m0 + tm + i) * N + n] = v;
      }
    }
}

// ============== per-row argmax + softmax entropy over p ==================
__global__ __launch_bounds__(256) void rowstats_kernel(
    const float* __restrict__ p, float* __restrict__ ent_new,
    int* __restrict__ cls) {
  const int b = blockIdx.x;
  const float* row = p + (size_t)b * CC;
  const int tid = threadIdx.x;
  const int lane = tid & 63, wid = tid >> 6;
  float mv = -INFINITY; int mi = 0x7fffffff;
  for (int c = tid; c < CC; c += 256) {
    float v = row[c];
    if (v > mv) { mv = v; mi = c; }
  }
#pragma unroll
  for (int o = 32; o > 0; o >>= 1) {
    float ov = __shfl_down(mv, o, 64);
    int oi = __shfl_down(mi, o, 64);
    if (ov > mv || (ov == mv && oi < mi)) { mv = ov; mi = oi; }
  }
  __shared__ float smv[4]; __shared__ int smi[4];
  if (lane == 0) { smv[wid] = mv; smi[wid] = mi; }
  __syncthreads();
  if (tid == 0) {
#pragma unroll
    for (int w = 1; w < 4; ++w)
      if (smv[w] > smv[0] || (smv[w] == smv[0] && smi[w] < smi[0])) {
        smv[0] = smv[w]; smi[0] = smi[w];
      }
  }
  __syncthreads();
  const float m = smv[0]; const int am = smi[0];
  float s = 0.f, t = 0.f;
  for (int c = tid; c < CC; c += 256) {
    float u = row[c] - m;
    float e = expf(u);
    s += e; t += u * e;
  }
#pragma unroll
  for (int o = 32; o > 0; o >>= 1) {
    s += __shfl_down(s, o, 64);
    t += __shfl_down(t, o, 64);
  }
  __shared__ float ssum[4], tsum[4];
  if (lane == 0) { ssum[wid] = s; tsum[wid] = t; }
  __syncthreads();
  if (tid == 0) {
    float S = ssum[0] + ssum[1] + ssum[2] + ssum[3];
    float T = tsum[0] + tsum[1] + tsum[2] + tsum[3];
    ent_new[b] = logf(S) - T / S;
    cls[b] = am;
  }
}

// ===================== class histogram / scan / scatter ==================
__global__ void hist_kernel(const int* __restrict__ labels_idx,
                            const int* __restrict__ cls,
                            int* __restrict__ counts) {
  int m = blockIdx.x * blockDim.x + threadIdx.x;
  if (m >= MM) return;
  int c = (m < NN) ? labels_idx[m] : cls[m - NN];
  atomicAdd(&counts[c], 1);
}

__global__ __launch_bounds__(1024) void scan_kernel(
    const int* __restrict__ counts, int* __restrict__ offsets,
    int* __restrict__ cursor) {
  __shared__ int buf[1024];
  const int tid = threadIdx.x;
  int v = (tid < CC) ? counts[tid] : 0;
  buf[tid] = v;
  __syncthreads();
  for (int o = 1; o < 1024; o <<= 1) {
    int t = (tid >= o) ? buf[tid - o] : 0;
    __syncthreads();
    buf[tid] += t;
    __syncthreads();
  }
  if (tid < CC) {
    int excl = buf[tid] - v;
    offsets[tid] = excl;
    cursor[tid] = excl;
  }
}

__global__ void scatter_kernel(const int* __restrict__ labels_idx,
                               const int* __restrict__ cls,
                               const float* __restrict__ ent_in,
                               const float* __restrict__ ent_new,
                               int* __restrict__ cursor,
                               float* __restrict__ ent_s,
                               int* __restrict__ idx_s) {
  int m = blockIdx.x * blockDim.x + threadIdx.x;
  if (m >= MM) return;
  int c, idx = m;
  float e;
  if (m < NN) { c = labels_idx[m]; e = ent_in[m]; }
  else        { c = cls[m - NN];   e = ent_new[m - NN]; }
  int pos = atomicAdd(&cursor[c], 1);
  ent_s[pos] = e;
  idx_s[pos] = idx;
}

// ====== per-class: select K lowest-entropy rows, sum normalized rows =====
__global__ __launch_bounds__(256) void class_weights_kernel(
    const float* __restrict__ supports_in,   // [N][512]
    const float* __restrict__ z,             // [B][512]
    const float* __restrict__ ent_s, const int* __restrict__ idx_s,
    const int* __restrict__ counts, const int* __restrict__ offsets,
    float* __restrict__ wn) {                // [C][512]
  const int c = blockIdx.x;
  const int tid = threadIdx.x;
  const int lane = tid & 63, wid = tid >> 6;
  const int n = counts[c], off = offsets[c];

  __shared__ int sel[FILTER_K];
  __shared__ float se[1024];
  __shared__ int si[1024];
  int seln;
  if (n <= FILTER_K) {
    seln = n;
    for (int i = tid; i < n; i += 256) sel[i] = idx_s[off + i];
  } else {
    // bitonic sort up to 1024 (count>1024 cannot happen for this data)
    int nn = n < 1024 ? n : 1024;
    for (int i = tid; i < 1024; i += 256) {
      if (i < nn) { se[i] = ent_s[off + i]; si[i] = idx_s[off + i]; }
      else        { se[i] = INFINITY;       si[i] = 0x7fffffff; }
    }
    __syncthreads();
    for (int k = 2; k <= 1024; k <<= 1)
      for (int j = k >> 1; j > 0; j >>= 1) {
        for (int i = tid; i < 1024; i += 256) {
          int ixj = i ^ j;
          if (ixj > i) {
            bool up = ((i & k) == 0);
            float e1 = se[i], e2 = se[ixj];
            int i1 = si[i], i2 = si[ixj];
            bool gt = (e1 > e2) || (e1 == e2 && i1 > i2);
            if (gt == up) { se[i] = e2; se[ixj] = e1; si[i] = i2; si[ixj] = i1; }
          }
        }
        __syncthreads();
      }
    seln = FILTER_K;
    for (int i = tid; i < FILTER_K; i += 256) sel[i] = si[i];
  }
  __syncthreads();

  // accumulate normalized rows; thread owns elements 2*tid, 2*tid+1
  float2 acc = make_float2(0.f, 0.f);
  __shared__ float wpart[4][4];  // [row-in-batch][wave]
  for (int base = 0; base < seln; base += 4) {
    float2 v[4]; float ps[4];
#pragma unroll
    for (int r2 = 0; r2 < 4; ++r2) {
      int j = base + r2;
      if (j < seln) {
        int ridx = sel[j];
        const float* ptr = (ridx < NN) ? (supports_in + (size_t)ridx * DD)
                                       : (z + (size_t)(ridx - NN) * DD);
        v[r2] = ((const float2*)ptr)[tid];
      } else {
        v[r2] = make_float2(0.f, 0.f);
      }
      ps[r2] = v[r2].x * v[r2].x + v[r2].y * v[r2].y;
    }
#pragma unroll
    for (int r2 = 0; r2 < 4; ++r2) {
      float s = ps[r2];
#pragma unroll
      for (int o = 32; o > 0; o >>= 1) s += __shfl_down(s, o, 64);
      if (lane == 0) wpart[r2][wid] = s;
    }
    __syncthreads();
#pragma unroll
    for (int r2 = 0; r2 < 4; ++r2) {
      float ss = wpart[r2][0] + wpart[r2][1] + wpart[r2][2] + wpart[r2][3];
      float scale = 1.0f / fmaxf(sqrtf(ss), 1e-12f);
      acc.x += v[r2].x * scale;
      acc.y += v[r2].y * scale;
    }
    __syncthreads();
  }

  // column normalization (over the 512 elements of this class column)
  float s = acc.x * acc.x + acc.y * acc.y;
#pragma unroll
  for (int o = 32; o > 0; o >>= 1) s += __shfl_down(s, o, 64);
  if (lane == 0) wpart[0][wid] = s;
  __syncthreads();
  float ss = wpart[0][0] + wpart[0][1] + wpart[0][2] + wpart[0][3];
  float scale = 1.0f / fmaxf(sqrtf(ss), 1e-12f);
  ((float2*)(wn + (size_t)c * DD))[tid] = make_float2(acc.x * scale, acc.y * scale);
}

// ============================ launcher ===================================
extern "C" void kernel_launch(void* const* d_in, const int* in_sizes, int n_in,
                              void* d_out, int out_size, void* d_ws, size_t ws_size,
                              hipStream_t stream) {
  (void)in_sizes; (void)n_in; (void)out_size; (void)ws_size;
  const float* x           = (const float*)d_in[0];
  const float* Wf          = (const float*)d_in[1];
  const float* Wc          = (const float*)d_in[2];
  const float* bc          = (const float*)d_in[3];
  const float* supports_in = (const float*)d_in[4];
  const float* ent_in      = (const float*)d_in[5];
  const int*   labels_idx  = (const int*)d_in[6];
  float* out = (float*)d_out;

  float* W = (float*)d_ws;
  float* z       = W + Z_OFF;
  float* p       = W + P_OFF;
  float* ent_new = W + ENTN_OFF;
  int*   cls     = (int*)(W + CLS_OFF);
  int*   counts  = (int*)(W + CNT_OFF);
  int*   offsets = (int*)(W + OFFS_OFF);
  int*   cursor  = (int*)(W + CUR_OFF);
  float* ent_s   = W + ENTS_OFF;
  int*   idx_s   = (int*)(W + IDXS_OFF);
  float* wn      = W + WN_OFF;

  // zero accumulators
  hipMemsetAsync(z, 0, (size_t)BB * DD * sizeof(float), stream);
  hipMemsetAsync(counts, 0, 1024 * sizeof(int), stream);

  // K1: z = x @ Wf   (M=256,N=512,K=2048, split-K 8)
  {
    dim3 grid(DD / BN1, BB / BM1, 8);
    gemm_split_k<<<grid, 256, 0, stream>>>(x, Wf, z, BB, DD, DIN, DIN / 8);
  }
  // K2: p = z @ Wc^T + bc   (M=256,N=1000,K=512)
  {
    dim3 grid((CC + BN2 - 1) / BN2, BB / BM2);
    gemm_abt<<<grid, 256, 0, stream>>>(z, Wc, bc, p, BB, CC, DD);
  }
  // argmax + entropy per row
  rowstats_kernel<<<BB, 256, 0, stream>>>(p, ent_new, cls);
  // class histogram
  hist_kernel<<<(MM + 255) / 256, 256, 0, stream>>>(labels_idx, cls, counts);
  // exclusive scan -> offsets, cursor
  scan_kernel<<<1, 1024, 0, stream>>>(counts, offsets, cursor);
  // scatter (ent, idx) into class segments
  scatter_kernel<<<(MM + 255) / 256, 256, 0, stream>>>(
      labels_idx, cls, ent_in, ent_new, cursor, ent_s, idx_s);
  // per-class selection + normalized accumulation + column norm
  class_weights_kernel<<<CC, 256, 0, stream>>>(
      supports_in, z, ent_s, idx_s, counts, offsets, wn);
  // K5: out = z @ wn^T   (M=256,N=1000,K=512)
  {
    dim3 grid((CC + BN2 - 1) / BN2, BB / BM2);
    gemm_abt<<<grid, 256, 0, stream>>>(z, wn, nullptr, out, BB, CC, DD);
  }
}